// Round 3
// baseline (309.502 us; speedup 1.0000x reference)
//
#include <hip/hip_runtime.h>

typedef __bf16 bf16x8 __attribute__((ext_vector_type(8)));
typedef __bf16 bf16x4 __attribute__((ext_vector_type(4)));
typedef float f32x4 __attribute__((ext_vector_type(4)));
typedef float f32x2 __attribute__((ext_vector_type(2)));

#define EPS 1e-5f

// ws layout (bytes):
//   mt  @ 0     : bf16[32][32]  alpha*M^T, M = W_col@W_row^T
//   bwt @ 2048  : bf16[64][16][16]  bw[g][b][c] -> [g][c][b]
//   lgc @ 34816 : bf16[1024]  L(gamma)
//   c2  @ 36864 : bf16[1024]  L(beta)+bias
// where L(v) = flip(blockdiag(v)) + alpha*Monarch(v)  (the full linear map)

__device__ float apply_L(const float* __restrict__ v, const float* __restrict__ bw,
                         const float* __restrict__ W_row, const float* __restrict__ W_col,
                         float alpha, int dp) {
    // block-diag + flip: pre-flip index f = 1023 - dp
    const int f = 1023 - dp, g = f >> 4, c = f & 15;
    float yb = 0.f;
    #pragma unroll
    for (int b = 0; b < 16; ++b) yb += v[g * 16 + b] * bw[g * 256 + b * 16 + c];
    // Monarch: dp = r*32 + s;  z = sum_k (sum_c v[r,c] Wc[c,k]) Wr[s,k]
    const int r = dp >> 5, s = dp & 31;
    float zm = 0.f;
    #pragma unroll 4
    for (int k = 0; k < 32; ++k) {
        float tmp = 0.f;
        #pragma unroll 8
        for (int cc = 0; cc < 32; ++cc) tmp += v[r * 32 + cc] * W_col[cc * 32 + k];
        zm += tmp * W_row[s * 32 + k];
    }
    return yb + alpha * zm;
}

__global__ __launch_bounds__(256) void hbsl_precompute(
    const float* __restrict__ gamma, const float* __restrict__ beta,
    const float* __restrict__ bw, const float* __restrict__ W_row,
    const float* __restrict__ W_col, const float* __restrict__ alpha_p,
    const float* __restrict__ bias,
    __bf16* __restrict__ mt, __bf16* __restrict__ bwt,
    __bf16* __restrict__ lgc, __bf16* __restrict__ c2)
{
    const int t = threadIdx.x;
    const float alpha = alpha_p[0];
    if (blockIdx.x == 0) {
        #pragma unroll
        for (int k = 0; k < 4; ++k) {
            int flat = t + 256 * k;
            int s = flat >> 5, c = flat & 31;
            float acc = 0.f;
            #pragma unroll 8
            for (int kk = 0; kk < 32; ++kk)
                acc += W_col[c * 32 + kk] * W_row[s * 32 + kk];
            mt[s * 32 + c] = (__bf16)(alpha * acc);
        }
    } else if (blockIdx.x <= 64) {
        int g = blockIdx.x - 1;
        int c = t >> 4, b = t & 15;
        bwt[g * 256 + c * 16 + b] = (__bf16)bw[g * 256 + b * 16 + c];
    } else if (blockIdx.x == 65) {
        #pragma unroll
        for (int k = 0; k < 4; ++k) {
            int dp = t + 256 * k;
            lgc[dp] = (__bf16)apply_L(gamma, bw, W_row, W_col, alpha, dp);
        }
    } else {
        #pragma unroll
        for (int k = 0; k < 4; ++k) {
            int dp = t + 256 * k;
            c2[dp] = (__bf16)(apply_L(beta, bw, W_row, W_col, alpha, dp) + bias[dp]);
        }
    }
}

// One block = 16 rows, 4 waves; wave wv owns out col-tiles [16wv, 16wv+16).
// out[row] = rstd*L(u)[row] + c1*Lgamma + C2,  u = bf16(x*gamma), c1 = -mu*rstd.
// Phase 1 writes u to LDS with NO dependency on the row stats.
__global__ __launch_bounds__(256, 4) void hbsl_main(
    const float* __restrict__ x, const float* __restrict__ gamma,
    const __bf16* __restrict__ mt, const __bf16* __restrict__ bwt,
    const __bf16* __restrict__ lgc, const __bf16* __restrict__ c2,
    float* __restrict__ out)
{
    __shared__ __bf16 xn[16 * 1032];     // u = bf16(x*gamma), pitch 1032
    __shared__ __bf16 lgc_s[1024];
    __shared__ __bf16 c2_s[1024];
    __shared__ float stats_s[32];        // [row]{rstd, c1}
    const int t = threadIdx.x;
    const int lane = t & 63;
    const int wv = t >> 6;
    const int q = lane >> 4, n = lane & 15;
    const int row = t >> 4, li = t & 15;
    const int rbase = blockIdx.x * 16;

    // --- Preloads (latency hidden under the x stream) ---
    bf16x8 mfrag0 = *(const bf16x8*)(mt + n * 32 + q * 8);
    bf16x8 mfrag1 = *(const bf16x8*)(mt + (16 + n) * 32 + q * 8);
    bf16x8 bwf[8];
    #pragma unroll
    for (int p = 0; p < 8; ++p) {
        const int o0 = wv * 16 + 2 * p;
        const int gp = 31 - (o0 >> 1);
        const int g = (q >= 2) ? (2 * gp + 1) : (2 * gp);
        const int e = (q >= 2) ? (q - 2) * 8 : q * 8;
        bwf[p] = *(const bf16x8*)(bwt + g * 256 + (15 - n) * 16 + e);
    }
    *(bf16x4*)(&lgc_s[t * 4]) = *(const bf16x4*)(lgc + t * 4);
    *(bf16x4*)(&c2_s[t * 4])  = *(const bf16x4*)(c2 + t * 4);

    // ---- Phase 1: stream x -> u into LDS; stats on the side ----
    const float* xr = x + (size_t)(rbase + row) * 1024;
    float s = 0.f, ss = 0.f;
    #pragma unroll
    for (int i = 0; i < 16; ++i) {
        const int col = li * 4 + i * 64;
        float4 xv = *(const float4*)(xr + col);
        float4 g4 = *(const float4*)(gamma + col);
        s += xv.x + xv.y + xv.z + xv.w;
        ss += xv.x * xv.x + xv.y * xv.y + xv.z * xv.z + xv.w * xv.w;
        bf16x4 v;
        v[0] = (__bf16)(xv.x * g4.x);
        v[1] = (__bf16)(xv.y * g4.y);
        v[2] = (__bf16)(xv.z * g4.z);
        v[3] = (__bf16)(xv.w * g4.w);
        *(bf16x4*)(&xn[row * 1032 + col]) = v;
    }
    #pragma unroll
    for (int m = 1; m < 16; m <<= 1) {
        s  += __shfl_xor(s, m, 64);
        ss += __shfl_xor(ss, m, 64);
    }
    const float mu = s * (1.f / 1024.f);
    const float rstd = rsqrtf(ss * (1.f / 1024.f) - mu * mu + EPS);
    if (li == 0) {
        stats_s[row * 2]     = rstd;
        stats_s[row * 2 + 1] = -mu * rstd;
    }
    __syncthreads();

    // ---- Phase 2: MFMA on raw u + affine epilogue, dwordx4 stores ----
    bf16x8 bz;
    #pragma unroll
    for (int i = 0; i < 8; ++i) bz[i] = (__bf16)0.f;
    const f32x4 zf = {0.f, 0.f, 0.f, 0.f};

    const f32x2 st = *(const f32x2*)(&stats_s[n * 2]);  // rstd, c1 of data row n

    #pragma unroll
    for (int p = 0; p < 8; ++p) {
        const int o0 = wv * 16 + 2 * p;
        const int r  = o0 >> 1;
        const int gp = 31 - r;

        bf16x8 az = *(const bf16x8*)(&xn[n * 1032 + r  * 32 + q * 8]);
        bf16x8 ay = *(const bf16x8*)(&xn[n * 1032 + gp * 32 + q * 8]);

        bf16x8 a0 = (q >= 2) ? bwf[p] : bz;   // tile o0: k in [16,32)
        bf16x8 a1 = (q <  2) ? bwf[p] : bz;   // tile o1: k in [0,16)

        f32x4 z0 = __builtin_amdgcn_mfma_f32_16x16x32_bf16(mfrag0, az, zf, 0, 0, 0);
        f32x4 z1 = __builtin_amdgcn_mfma_f32_16x16x32_bf16(mfrag1, az, zf, 0, 0, 0);
        f32x4 y0 = __builtin_amdgcn_mfma_f32_16x16x32_bf16(a0, ay, zf, 0, 0, 0);
        f32x4 y1 = __builtin_amdgcn_mfma_f32_16x16x32_bf16(a1, ay, zf, 0, 0, 0);

        bf16x4 lg0 = *(const bf16x4*)(&lgc_s[o0 * 16 + q * 4]);
        bf16x4 lg1 = *(const bf16x4*)(&lgc_s[o0 * 16 + 16 + q * 4]);
        bf16x4 cc0 = *(const bf16x4*)(&c2_s[o0 * 16 + q * 4]);
        bf16x4 cc1 = *(const bf16x4*)(&c2_s[o0 * 16 + 16 + q * 4]);

        f32x4 r0, r1;
        #pragma unroll
        for (int e = 0; e < 4; ++e) {
            r0[e] = fmaf(y0[e] + z0[e], st[0], fmaf((float)lg0[e], st[1], (float)cc0[e]));
            r1[e] = fmaf(y1[e] + z1[e], st[0], fmaf((float)lg1[e], st[1], (float)cc1[e]));
        }
        float* op = out + (size_t)(rbase + n) * 1024 + o0 * 16 + q * 4;
        *(f32x4*)op        = r0;
        *(f32x4*)(op + 16) = r1;
    }
}

extern "C" void kernel_launch(void* const* d_in, const int* in_sizes, int n_in,
                              void* d_out, int out_size, void* d_ws, size_t ws_size,
                              hipStream_t stream) {
    const float* x      = (const float*)d_in[0];
    const float* gamma  = (const float*)d_in[1];
    const float* beta   = (const float*)d_in[2];
    const float* bw     = (const float*)d_in[3];
    const float* W_row  = (const float*)d_in[4];
    const float* W_col  = (const float*)d_in[5];
    const float* alpha  = (const float*)d_in[6];
    const float* bias   = (const float*)d_in[7];
    float* o = (float*)d_out;

    __bf16* mt  = (__bf16*)d_ws;                          // 2048 B
    __bf16* bwt = (__bf16*)((char*)d_ws + 2048);          // 32768 B
    __bf16* lgc = (__bf16*)((char*)d_ws + 34816);         // 2048 B
    __bf16* c2  = (__bf16*)((char*)d_ws + 36864);         // 2048 B

    const int N = in_sizes[0] / 1024;                     // 32768 rows

    hipLaunchKernelGGL(hbsl_precompute, dim3(67), dim3(256), 0, stream,
                       gamma, beta, bw, W_row, W_col, alpha, bias, mt, bwt, lgc, c2);
    hipLaunchKernelGGL(hbsl_main, dim3(N / 16), dim3(256), 0, stream,
                       x, gamma, mt, bwt, lgc, c2, o);
}